// Round 9
// baseline (1221.328 us; speedup 1.0000x reference)
//
#include <hip/hip_runtime.h>
#include <stdint.h>

typedef unsigned short u16;
typedef uint32_t u32;
typedef short s16x8 __attribute__((ext_vector_type(8)));
typedef float fx16 __attribute__((ext_vector_type(16)));

#define B_   256
#define H_   1024
#define BH_  (B_ * H_)                  // 262144
#define WPE  ((size_t)2 * 4096 * 2048)  // W pack elems
#define XPE  ((size_t)15 * BH_)
#define HPE  ((size_t)32 * BH_)
#define NT   32                         // K-steps (BK=64)

__device__ __forceinline__ u16 bf16_rn(float x) {
    union { float f; u32 u; } v; v.f = x;
    return (u16)((v.u + 0x7FFFu + ((v.u >> 16) & 1u)) >> 16);
}
__device__ __forceinline__ float sigf(float x) {
    return __builtin_amdgcn_rcpf(1.0f + __expf(-x));
}
__device__ __forceinline__ float tanh_f(float x) {
    return 1.0f - 2.0f * __builtin_amdgcn_rcpf(1.0f + __expf(2.0f * x));
}

// ---------------------------------------------------------------------------
// Pack W into MFMA-B fragment order, bf16. Chunk w = ((layer*4+gate)*32+cg)*128+k16;
// lane l -> W[gate*1024+cg*32+(l&31)][k16*16+(l>>5)*8+e].
// ---------------------------------------------------------------------------
__global__ __launch_bounds__(256)
void pack_weights(const float* __restrict__ Wih, const float* __restrict__ Whh,
                  u16* __restrict__ wp)
{
    const int gt = blockIdx.x * 256 + threadIdx.x;
    const int w = gt >> 6, lane = gt & 63;
    const int k16 = w & 127, cg = (w >> 7) & 31, gate = (w >> 12) & 3, layer = w >> 14;
    const int row = gate * 1024 + cg * 32 + (lane & 31);
    const int k = k16 * 16 + (lane >> 5) * 8;
    const float* src = (k < 1024)
        ? Wih + ((size_t)layer * 4096 + row) * 1024 + k
        : Whh + ((size_t)layer * 4096 + row) * 1024 + (k - 1024);
    const float4 v0 = *(const float4*)src;
    const float4 v1 = *(const float4*)(src + 4);
    const float a[8] = {v0.x, v0.y, v0.z, v0.w, v1.x, v1.y, v1.z, v1.w};
    union { u16 s[8]; uint4 v; } hi;
    #pragma unroll
    for (int e = 0; e < 8; ++e) hi.s[e] = bf16_rn(a[e]);
    *(uint4*)(wp + (size_t)w * 512 + (size_t)lane * 8) = hi.v;
}

__global__ __launch_bounds__(256)
void pack_x(const float* __restrict__ input, const float* __restrict__ bridge,
            u16* __restrict__ xp)
{
    const int gt = blockIdx.x * 256 + threadIdx.x;
    const int w = gt >> 6, lane = gt & 63;
    const int k16 = w & 63, btile = (w >> 6) & 7, n1 = w >> 9;
    const int b = btile * 32 + (lane & 31);
    const int k = k16 * 16 + (lane >> 5) * 8;
    const float* src = (k < 512)
        ? input  + ((size_t)n1 * 256 + b) * 512 + k
        : bridge + ((size_t)n1 * 256 + b) * 512 + (k - 512);
    const float4 v0 = *(const float4*)src;
    const float4 v1 = *(const float4*)(src + 4);
    const float a[8] = {v0.x, v0.y, v0.z, v0.w, v1.x, v1.y, v1.z, v1.w};
    union { u16 s[8]; uint4 v; } hi;
    #pragma unroll
    for (int e = 0; e < 8; ++e) hi.s[e] = bf16_rn(a[e]);
    *(uint4*)(xp + (size_t)w * 512 + (size_t)lane * 8) = hi.v;
}

__global__ __launch_bounds__(256)
void bias_sum_k(const float* __restrict__ bih, const float* __restrict__ bhh,
                float* __restrict__ bs)
{
    const int i = blockIdx.x * 256 + threadIdx.x;
    if (i < 8192) bs[i] = bih[i] + bhh[i];
}

// ---------------------------------------------------------------------------
// Whole-tree dataflow kernel. 30 cells (topo order) x 64 blocks = 1920 blocks.
// Per-block structure = r8's proven fused cell (128x128 tile, 4 waves,
// single-buffered 32KB global_load_lds staging, 32 K-steps, fused gates).
// Dependencies enforced in-kernel:
//   layer-1 block: wait done[node,l0]==64 before step 0 (own-h half),
//   any block:     wait done[par,layer]==64 before step 16 (parent-h half).
// Producers: stores -> __syncthreads (drains vmcnt) -> RELEASE/agent atomicAdd.
// Consumers: ACQUIRE/agent spin load (invalidates L1/L2 for cross-XCD h).
// Deadlock-free under monotone WG dispatch (stream-K precedent): topo order
// guarantees the earliest incomplete cell's deps are already complete.
// ---------------------------------------------------------------------------
__constant__ signed char T_NODE[30] = {1,1,2,5,8,2,5,8,3,6,9,12,3,6,9,12,
                                       4,7,10,13,4,7,10,13,11,14,11,14,15,15};
__constant__ signed char T_PAR[30]  = {0,0,1,1,1,1,1,1,2,5,8,8,2,5,8,8,
                                       3,6,9,12,3,6,9,12,10,13,10,13,14,14};
__constant__ signed char T_LAY[30]  = {0,1,0,0,0,1,1,1,0,0,0,0,1,1,1,1,
                                       0,0,0,0,1,1,1,1,0,0,1,1,0,1};

__device__ __forceinline__ void block_wait(int* p) {
    if (threadIdx.x == 0) {
        while (__hip_atomic_load(p, __ATOMIC_ACQUIRE,
                                 __HIP_MEMORY_SCOPE_AGENT) < 64) {
            __builtin_amdgcn_s_sleep(8);
        }
    }
    __syncthreads();
}

__global__ __launch_bounds__(256, 3)
void cell_tree(const u16* __restrict__ wp, const u16* __restrict__ xp,
               u16* __restrict__ hp, float* __restrict__ c_buf,
               const float* __restrict__ bsum, float* __restrict__ out,
               int* __restrict__ done)
{
    __shared__ __align__(16) char SMEM[37376];
    u16*   AL   = (u16*)SMEM;            // [btl(4)][kk(4)][512] = 16 KB
    u16*   WL   = AL + 8192;             // [g(4)][kk(4)][512]   = 16 KB
    float* gbuf = (float*)SMEM;          // [64][129] f32 (epilogue)
    u16*   tbuf = (u16*)(SMEM + 33024);  // [64][33] u16 (epilogue)

    const int bid  = blockIdx.x;
    const int cidx = bid >> 6;
    const int u    = bid & 63;
    const int hhblk = 4 * (u & 7) + ((u >> 3) & 3);   // 0..31, XCD-stable
    const int mblk  = u >> 5;                          // 0..1
    const int node = T_NODE[cidx], par = T_PAR[cidx], layer = T_LAY[cidx];
    const int tid = threadIdx.x, wv = tid >> 6, lane = tid & 63;
    const int mw = wv >> 1, nw = wv & 1;
    const int tg = tid >> 6;
    const int tl8 = (tid & 63) * 8;

    // A segment bases (seg0 = K 0..1023, seg1 = K 1024..2047)
    const u16 *A0, *A1;
    if (layer == 0) {
        A0 = xp + (size_t)(node - 1) * BH_;
        A1 = hp + (size_t)(par * 2 + 0) * BH_;
    } else {
        A0 = hp + (size_t)(node * 2 + 0) * BH_;
        A1 = hp + (size_t)(par * 2 + 1) * BH_;
    }
    size_t wsrc[4];
    #pragma unroll
    for (int g = 0; g < 4; ++g)
        wsrc[g] = ((size_t)((layer * 4 + g) * 32 + hhblk) * 128 + tg) * 512
                + (size_t)tl8;

    // dependency indices
    const int w1 = (par > 0) ? (par * 2 + layer) : -1;
    if (layer == 1) block_wait(done + node * 2);      // own l0 h before step 0

    fx16 acc[2][2];
    #pragma unroll
    for (int m = 0; m < 2; ++m)
        #pragma unroll
        for (int n = 0; n < 2; ++n)
            #pragma unroll
            for (int r = 0; r < 16; ++r) acc[m][n][r] = 0.0f;

    #pragma unroll 1
    for (int t = 0; t < NT; ++t) {
        if (t == 16 && w1 >= 0) block_wait(done + w1);  // parent h before seg1
        // ---- stage: A 16KB + W 16KB
        const u16* As = (t < 16) ? A0 : A1;
        const int k16 = (t & 15) * 4 + tg;
        #pragma unroll
        for (int i = 0; i < 4; ++i) {
            __builtin_amdgcn_global_load_lds(
                (const __attribute__((address_space(1))) void*)
                    (As + ((size_t)(mblk * 4 + i) * 64 + k16) * 512 + tl8),
                (__attribute__((address_space(3))) void*)
                    (AL + (i * 4 + tg) * 512 + tl8),
                16, 0, 0);
        }
        #pragma unroll
        for (int i = 0; i < 4; ++i) {
            __builtin_amdgcn_global_load_lds(
                (const __attribute__((address_space(1))) void*)
                    (wp + wsrc[i] + (size_t)t * 4 * 512),
                (__attribute__((address_space(3))) void*)
                    (WL + (i * 4 + tg) * 512 + tl8),
                16, 0, 0);
        }
        __syncthreads();
        // ---- compute
        #pragma unroll
        for (int kk = 0; kk < 4; ++kk) {
            s16x8 a[2], w[2];
            #pragma unroll
            for (int m = 0; m < 2; ++m)
                a[m] = *(const s16x8*)(AL + ((mw * 2 + m) * 4 + kk) * 512 + lane * 8);
            #pragma unroll
            for (int n = 0; n < 2; ++n)
                w[n] = *(const s16x8*)(WL + ((nw * 2 + n) * 4 + kk) * 512 + lane * 8);
            #pragma unroll
            for (int m = 0; m < 2; ++m)
                #pragma unroll
                for (int n = 0; n < 2; ++n)
                    acc[m][n] = __builtin_amdgcn_mfma_f32_32x32x16_bf16(
                        a[m], w[n], acc[m][n], 0, 0, 0);
        }
        __syncthreads();
    }

    // ---- fused epilogue (identical to r8)
    const int hhl  = tid & 31;
    const int colg = hhblk * 32 + hhl;
    float bs4[4];
    #pragma unroll
    for (int g = 0; g < 4; ++g)
        bs4[g] = bsum[layer * 4096 + g * 1024 + colg];

    const float* cpar = c_buf + (size_t)(par * 2 + layer) * BH_ + colg;
    float*       cnew = c_buf + (size_t)(node * 2 + layer) * BH_ + colg;
    float*       outp = out + (size_t)(node - 1) * BH_ + colg;
    u16*         hpn  = hp + (size_t)(node * 2 + layer) * BH_;

    #pragma unroll
    for (int p = 0; p < 2; ++p) {
        __syncthreads();
        if (mw == p) {
            #pragma unroll
            for (int m = 0; m < 2; ++m) {
                #pragma unroll
                for (int n = 0; n < 2; ++n) {
                    const int col = (nw * 2 + n) * 32 + (lane & 31);
                    #pragma unroll
                    for (int r = 0; r < 16; ++r) {
                        const int row_l = m * 32 + 4 * (lane >> 5)
                                        + (r & 3) + 8 * (r >> 2);
                        gbuf[row_l * 129 + col] = acc[m][n][r];
                    }
                }
            }
        }
        __syncthreads();
        #pragma unroll
        for (int e = 0; e < 8; ++e) {
            const int row_l = e * 8 + (tid >> 5);
            const size_t grow = (size_t)(mblk * 128 + p * 64 + row_l) * 1024;
            const float gi = gbuf[row_l * 129 + 0 * 32 + hhl] + bs4[0];
            const float gf = gbuf[row_l * 129 + 1 * 32 + hhl] + bs4[1];
            const float gg = gbuf[row_l * 129 + 2 * 32 + hhl] + bs4[2];
            const float go = gbuf[row_l * 129 + 3 * 32 + hhl] + bs4[3];
            const float cp = cpar[grow];
            const float cn = sigf(gf) * cp + sigf(gi) * tanh_f(gg);
            const float hn = sigf(go) * tanh_f(cn);
            cnew[grow] = cn;
            if (layer == 1) outp[grow] = hn;
            tbuf[row_l * 33 + hhl] = bf16_rn(hn);
        }
        __syncthreads();
        {
            const int j = wv >> 1, q = wv & 1;
            const int bt   = mblk * 4 + p * 2 + j;
            const int k16h = hhblk * 2 + q;
            union { u16 s[8]; uint4 v; } pk;
            #pragma unroll
            for (int e = 0; e < 8; ++e)
                pk.s[e] = tbuf[(j * 32 + (lane & 31)) * 33
                               + q * 16 + (lane >> 5) * 8 + e];
            *(uint4*)(hpn + ((size_t)bt * 64 + k16h) * 512 + lane * 8) = pk.v;
        }
    }

    // ---- publish: stores drained by __syncthreads; release to agent scope
    __syncthreads();
    if (tid == 0)
        __hip_atomic_fetch_add(done + node * 2 + layer, 1,
                               __ATOMIC_RELEASE, __HIP_MEMORY_SCOPE_AGENT);
}

// ---------------------------------------------------------------------------
extern "C" void kernel_launch(void* const* d_in, const int* in_sizes, int n_in,
                              void* d_out, int out_size, void* d_ws, size_t ws_size,
                              hipStream_t stream)
{
    const float* input  = (const float*)d_in[0];
    const float* bridge = (const float*)d_in[1];
    const float* Wih    = (const float*)d_in[2];
    const float* Whh    = (const float*)d_in[3];
    const float* bih    = (const float*)d_in[4];
    const float* bhh    = (const float*)d_in[5];
    float* out = (float*)d_out;

    u16* wp = (u16*)d_ws;
    u16* xp = wp + WPE;
    u16* hp = xp + XPE;
    float* c_buf = (float*)(hp + HPE);
    float* bsum  = c_buf + HPE;
    int*   done  = (int*)(bsum + 8192);

    hipMemsetAsync(hp, 0, (size_t)2 * BH_ * sizeof(u16), stream);
    hipMemsetAsync(c_buf, 0, (size_t)2 * BH_ * sizeof(float), stream);
    hipMemsetAsync(done, 0, 32 * sizeof(int), stream);

    bias_sum_k<<<32, 256, 0, stream>>>(bih, bhh, bsum);
    pack_weights<<<8192, 256, 0, stream>>>(Wih, Whh, wp);
    pack_x<<<1920, 256, 0, stream>>>(input, bridge, xp);

    cell_tree<<<dim3(30 * 64), 256, 0, stream>>>(
        wp, xp, hp, c_buf, bsum, out, done);
}

// Round 10
// 465.387 us; speedup vs baseline: 2.6243x; 2.6243x over previous
//
#include <hip/hip_runtime.h>
#include <stdint.h>

typedef unsigned short u16;
typedef uint32_t u32;
typedef short s16x8 __attribute__((ext_vector_type(8)));
typedef float fx16 __attribute__((ext_vector_type(16)));

#define B_   256
#define H_   1024
#define BH_  (B_ * H_)                  // 262144
#define WPE  ((size_t)2 * 4096 * 2048)  // W pack elems
#define XPE  ((size_t)15 * BH_)
#define HPE  ((size_t)32 * BH_)
#define NT   32                         // K-steps (BK=64)
#define GPLANE ((size_t)B_ * 4096)      // one partial plane (f32 elems)

struct Stage { int node[8]; int par[8]; int layer[8]; int cnt; };

__device__ __forceinline__ u16 bf16_rn(float x) {
    union { float f; u32 u; } v; v.f = x;
    return (u16)((v.u + 0x7FFFu + ((v.u >> 16) & 1u)) >> 16);
}
__device__ __forceinline__ float sigf(float x) {
    return __builtin_amdgcn_rcpf(1.0f + __expf(-x));
}
__device__ __forceinline__ float tanh_f(float x) {
    return 1.0f - 2.0f * __builtin_amdgcn_rcpf(1.0f + __expf(2.0f * x));
}

// ---------------------------------------------------------------------------
// Pack W into MFMA-B fragment order, bf16. Chunk w = ((layer*4+gate)*32+cg)*128+k16;
// lane l -> W[gate*1024+cg*32+(l&31)][k16*16+(l>>5)*8+e].
// ---------------------------------------------------------------------------
__global__ __launch_bounds__(256)
void pack_weights(const float* __restrict__ Wih, const float* __restrict__ Whh,
                  u16* __restrict__ wp)
{
    const int gt = blockIdx.x * 256 + threadIdx.x;
    const int w = gt >> 6, lane = gt & 63;
    const int k16 = w & 127, cg = (w >> 7) & 31, gate = (w >> 12) & 3, layer = w >> 14;
    const int row = gate * 1024 + cg * 32 + (lane & 31);
    const int k = k16 * 16 + (lane >> 5) * 8;
    const float* src = (k < 1024)
        ? Wih + ((size_t)layer * 4096 + row) * 1024 + k
        : Whh + ((size_t)layer * 4096 + row) * 1024 + (k - 1024);
    const float4 v0 = *(const float4*)src;
    const float4 v1 = *(const float4*)(src + 4);
    const float a[8] = {v0.x, v0.y, v0.z, v0.w, v1.x, v1.y, v1.z, v1.w};
    union { u16 s[8]; uint4 v; } hi;
    #pragma unroll
    for (int e = 0; e < 8; ++e) hi.s[e] = bf16_rn(a[e]);
    *(uint4*)(wp + (size_t)w * 512 + (size_t)lane * 8) = hi.v;
}

__global__ __launch_bounds__(256)
void pack_x(const float* __restrict__ input, const float* __restrict__ bridge,
            u16* __restrict__ xp)
{
    const int gt = blockIdx.x * 256 + threadIdx.x;
    const int w = gt >> 6, lane = gt & 63;
    const int k16 = w & 63, btile = (w >> 6) & 7, n1 = w >> 9;
    const int b = btile * 32 + (lane & 31);
    const int k = k16 * 16 + (lane >> 5) * 8;
    const float* src = (k < 512)
        ? input  + ((size_t)n1 * 256 + b) * 512 + k
        : bridge + ((size_t)n1 * 256 + b) * 512 + (k - 512);
    const float4 v0 = *(const float4*)src;
    const float4 v1 = *(const float4*)(src + 4);
    const float a[8] = {v0.x, v0.y, v0.z, v0.w, v1.x, v1.y, v1.z, v1.w};
    union { u16 s[8]; uint4 v; } hi;
    #pragma unroll
    for (int e = 0; e < 8; ++e) hi.s[e] = bf16_rn(a[e]);
    *(uint4*)(xp + (size_t)w * 512 + (size_t)lane * 8) = hi.v;
}

__global__ __launch_bounds__(256)
void bias_sum_k(const float* __restrict__ bih, const float* __restrict__ bhh,
                float* __restrict__ bs)
{
    const int i = blockIdx.x * 256 + threadIdx.x;
    if (i < 8192) bs[i] = bih[i] + bhh[i];
}

// ---------------------------------------------------------------------------
// Fused cell, m97-order double-buffered loop. Block = 256 thr (4 waves),
// tile M=128 x N=128 (4 gates x 32 hh). LDS 64 KB: 2 bufs x (16KB A + 16KB W).
// Per step: sync -> STAGE(t+1, buf^1) -> COMPUTE(t, buf)  (RT latency of the
// t+1 loads hides under COMPUTE(t); single barrier per step).
// bid map: mblk = bid >= grid/2 -> the two mblk-blocks of one (cell,hhblk)
// are bid-distance grid/2 apart (=256 for cnt=8 -> same CU, W stream L1-shared).
// ---------------------------------------------------------------------------
__global__ __launch_bounds__(256, 2)
void cell_fused(const u16* __restrict__ wp, const u16* __restrict__ xp,
                u16* __restrict__ hp, float* __restrict__ c_buf,
                const float* __restrict__ bsum, float* __restrict__ out,
                Stage st)
{
    __shared__ __align__(16) char SMEM[65536];
    u16*   BUF  = (u16*)SMEM;            // buf b: A at b*16384, W at b*16384+8192
    float* gbuf = (float*)SMEM;          // epilogue overlay [64][129] f32
    u16*   tbuf = (u16*)(SMEM + 33024);  // epilogue overlay [64][33] u16

    const int bid  = blockIdx.x;
    const int half = gridDim.x >> 1;
    const int mblk = (bid >= half) ? 1 : 0;
    const int v    = bid - mblk * half;
    const int hhblk = 4 * (v & 7) + ((v >> 3) & 3);   // 0..31, XCD-stable
    const int cell  = v >> 5;
    const int node = st.node[cell], par = st.par[cell], layer = st.layer[cell];
    const int tid = threadIdx.x, wv = tid >> 6, lane = tid & 63;
    const int mw = wv >> 1, nw = wv & 1;
    const int tg = tid >> 6;
    const int tl8 = (tid & 63) * 8;

    const u16 *A0, *A1;
    if (layer == 0) {
        A0 = xp + (size_t)(node - 1) * BH_;
        A1 = hp + (size_t)(par * 2 + 0) * BH_;
    } else {
        A0 = hp + (size_t)(node * 2 + 0) * BH_;
        A1 = hp + (size_t)(par * 2 + 1) * BH_;
    }
    size_t wsrc[4];
    #pragma unroll
    for (int g = 0; g < 4; ++g)
        wsrc[g] = ((size_t)((layer * 4 + g) * 32 + hhblk) * 128 + tg) * 512
                + (size_t)tl8;

    #define STAGE(T, BB) do {                                                  \
        const u16* As_ = ((T) < 16) ? A0 : A1;                                 \
        const int k16_ = ((T) & 15) * 4 + tg;                                  \
        _Pragma("unroll")                                                      \
        for (int i_ = 0; i_ < 4; ++i_) {                                       \
            __builtin_amdgcn_global_load_lds(                                  \
                (const __attribute__((address_space(1))) void*)                \
                    (As_ + ((size_t)(mblk * 4 + i_) * 64 + k16_) * 512 + tl8), \
                (__attribute__((address_space(3))) void*)                      \
                    (BUF + (BB) * 16384 + (i_ * 4 + tg) * 512 + tl8),          \
                16, 0, 0);                                                     \
        }                                                                      \
        _Pragma("unroll")                                                      \
        for (int i_ = 0; i_ < 4; ++i_) {                                       \
            __builtin_amdgcn_global_load_lds(                                  \
                (const __attribute__((address_space(1))) void*)                \
                    (wp + wsrc[i_] + (size_t)(T) * 2048),                      \
                (__attribute__((address_space(3))) void*)                      \
                    (BUF + (BB) * 16384 + 8192 + (i_ * 4 + tg) * 512 + tl8),   \
                16, 0, 0);                                                     \
        }                                                                      \
    } while (0)

    #define COMPUTE(BB) do {                                                   \
        _Pragma("unroll")                                                      \
        for (int kk_ = 0; kk_ < 4; ++kk_) {                                    \
            s16x8 a_[2], w_[2];                                                \
            _Pragma("unroll")                                                  \
            for (int m_ = 0; m_ < 2; ++m_)                                     \
                a_[m_] = *(const s16x8*)(BUF + (BB) * 16384                    \
                        + ((mw * 2 + m_) * 4 + kk_) * 512 + lane * 8);         \
            _Pragma("unroll")                                                  \
            for (int n_ = 0; n_ < 2; ++n_)                                     \
                w_[n_] = *(const s16x8*)(BUF + (BB) * 16384 + 8192             \
                        + ((nw * 2 + n_) * 4 + kk_) * 512 + lane * 8);         \
            _Pragma("unroll")                                                  \
            for (int m_ = 0; m_ < 2; ++m_)                                     \
                _Pragma("unroll")                                              \
                for (int n_ = 0; n_ < 2; ++n_)                                 \
                    acc[m_][n_] = __builtin_amdgcn_mfma_f32_32x32x16_bf16(     \
                        a_[m_], w_[n_], acc[m_][n_], 0, 0, 0);                 \
        }                                                                      \
    } while (0)

    fx16 acc[2][2];
    #pragma unroll
    for (int m = 0; m < 2; ++m)
        #pragma unroll
        for (int n = 0; n < 2; ++n)
            #pragma unroll
            for (int r = 0; r < 16; ++r) acc[m][n][r] = 0.0f;

    STAGE(0, 0);
    #pragma unroll 1
    for (int t = 0; t < NT; ++t) {
        __syncthreads();                         // STAGE(t) landed; buf t&1 free
        if (t + 1 < NT) STAGE(t + 1, (t + 1) & 1);
        COMPUTE(t & 1);
    }

    // ---- fused epilogue (C/D: col=lane&31, row=(r&3)+8*(r>>2)+4*(lane>>5))
    const int hhl  = tid & 31;
    const int colg = hhblk * 32 + hhl;
    float bs4[4];
    #pragma unroll
    for (int g = 0; g < 4; ++g)
        bs4[g] = bsum[layer * 4096 + g * 1024 + colg];

    const float* cpar = c_buf + (size_t)(par * 2 + layer) * BH_ + colg;
    float*       cnew = c_buf + (size_t)(node * 2 + layer) * BH_ + colg;
    float*       outp = out + (size_t)(node - 1) * BH_ + colg;
    u16*         hpn  = hp + (size_t)(node * 2 + layer) * BH_;

    #pragma unroll
    for (int p = 0; p < 2; ++p) {
        __syncthreads();
        if (mw == p) {
            #pragma unroll
            for (int m = 0; m < 2; ++m) {
                #pragma unroll
                for (int n = 0; n < 2; ++n) {
                    const int col = (nw * 2 + n) * 32 + (lane & 31);
                    #pragma unroll
                    for (int r = 0; r < 16; ++r) {
                        const int row_l = m * 32 + 4 * (lane >> 5)
                                        + (r & 3) + 8 * (r >> 2);
                        gbuf[row_l * 129 + col] = acc[m][n][r];
                    }
                }
            }
        }
        __syncthreads();
        #pragma unroll
        for (int e = 0; e < 8; ++e) {
            const int row_l = e * 8 + (tid >> 5);
            const size_t grow = (size_t)(mblk * 128 + p * 64 + row_l) * 1024;
            const float gi = gbuf[row_l * 129 + 0 * 32 + hhl] + bs4[0];
            const float gf = gbuf[row_l * 129 + 1 * 32 + hhl] + bs4[1];
            const float gg = gbuf[row_l * 129 + 2 * 32 + hhl] + bs4[2];
            const float go = gbuf[row_l * 129 + 3 * 32 + hhl] + bs4[3];
            const float cp = cpar[grow];
            const float cn = sigf(gf) * cp + sigf(gi) * tanh_f(gg);
            const float hn = sigf(go) * tanh_f(cn);
            cnew[grow] = cn;
            if (layer == 1) outp[grow] = hn;
            tbuf[row_l * 33 + hhl] = bf16_rn(hn);
        }
        __syncthreads();
        {
            const int j = wv >> 1, q = wv & 1;
            const int bt   = mblk * 4 + p * 2 + j;
            const int k16h = hhblk * 2 + q;
            union { u16 s[8]; uint4 v; } pk;
            #pragma unroll
            for (int e = 0; e < 8; ++e)
                pk.s[e] = tbuf[(j * 32 + (lane & 31)) * 33
                               + q * 16 + (lane >> 5) * 8 + e];
            *(uint4*)(hpn + ((size_t)bt * 64 + k16h) * 512 + lane * 8) = pk.v;
        }
    }
    #undef STAGE
    #undef COMPUTE
}

// ---------------------------------------------------------------------------
// Split-K GEMM for small stages: same tile/loop, K range [sp*NTs*64, ...),
// writes f32 partials to gpart plane (cell*S+sp).
// ---------------------------------------------------------------------------
__global__ __launch_bounds__(256, 2)
void cell_gemm_sk(const u16* __restrict__ wp, const u16* __restrict__ xp,
                  const u16* __restrict__ hp, float* __restrict__ gpart,
                  Stage st, int S, int NTs)
{
    __shared__ __align__(16) char SMEM[65536];
    u16* BUF = (u16*)SMEM;

    const int bid  = blockIdx.x;
    const int per  = 64 * S;
    const int cell = bid / per;
    const int rr   = bid % per;
    const int sp   = rr >> 6;
    const int u    = rr & 63;
    const int hhblk = 4 * (u & 7) + ((u >> 3) & 3);
    const int mblk  = u >> 5;
    const int node = st.node[cell], par = st.par[cell], layer = st.layer[cell];
    const int tid = threadIdx.x, wv = tid >> 6, lane = tid & 63;
    const int mw = wv >> 1, nw = wv & 1;
    const int tg = tid >> 6;
    const int tl8 = (tid & 63) * 8;

    const u16 *A0, *A1;
    if (layer == 0) {
        A0 = xp + (size_t)(node - 1) * BH_;
        A1 = hp + (size_t)(par * 2 + 0) * BH_;
    } else {
        A0 = hp + (size_t)(node * 2 + 0) * BH_;
        A1 = hp + (size_t)(par * 2 + 1) * BH_;
    }
    size_t wsrc[4];
    #pragma unroll
    for (int g = 0; g < 4; ++g)
        wsrc[g] = ((size_t)((layer * 4 + g) * 32 + hhblk) * 128 + tg) * 512
                + (size_t)tl8;

    #define STAGE(T, BB) do {                                                  \
        const u16* As_ = ((T) < 16) ? A0 : A1;                                 \
        const int k16_ = ((T) & 15) * 4 + tg;                                  \
        _Pragma("unroll")                                                      \
        for (int i_ = 0; i_ < 4; ++i_) {                                       \
            __builtin_amdgcn_global_load_lds(                                  \
                (const __attribute__((address_space(1))) void*)                \
                    (As_ + ((size_t)(mblk * 4 + i_) * 64 + k16_) * 512 + tl8), \
                (__attribute__((address_space(3))) void*)                      \
                    (BUF + (BB) * 16384 + (i_ * 4 + tg) * 512 + tl8),          \
                16, 0, 0);                                                     \
        }                                                                      \
        _Pragma("unroll")                                                      \
        for (int i_ = 0; i_ < 4; ++i_) {                                       \
            __builtin_amdgcn_global_load_lds(                                  \
                (const __attribute__((address_space(1))) void*)                \
                    (wp + wsrc[i_] + (size_t)(T) * 2048),                      \
                (__attribute__((address_space(3))) void*)                      \
                    (BUF + (BB) * 16384 + 8192 + (i_ * 4 + tg) * 512 + tl8),   \
                16, 0, 0);                                                     \
        }                                                                      \
    } while (0)

    #define COMPUTE(BB) do {                                                   \
        _Pragma("unroll")                                                      \
        for (int kk_ = 0; kk_ < 4; ++kk_) {                                    \
            s16x8 a_[2], w_[2];                                                \
            _Pragma("unroll")                                                  \
            for (int m_ = 0; m_ < 2; ++m_)                                     \
                a_[m_] = *(const s16x8*)(BUF + (BB) * 16384                    \
                        + ((mw * 2 + m_) * 4 + kk_) * 512 + lane * 8);         \
            _Pragma("unroll")                                                  \
            for (int n_ = 0; n_ < 2; ++n_)                                     \
                w_[n_] = *(const s16x8*)(BUF + (BB) * 16384 + 8192             \
                        + ((nw * 2 + n_) * 4 + kk_) * 512 + lane * 8);         \
            _Pragma("unroll")                                                  \
            for (int m_ = 0; m_ < 2; ++m_)                                     \
                _Pragma("unroll")                                              \
                for (int n_ = 0; n_ < 2; ++n_)                                 \
                    acc[m_][n_] = __builtin_amdgcn_mfma_f32_32x32x16_bf16(     \
                        a_[m_], w_[n_], acc[m_][n_], 0, 0, 0);                 \
        }                                                                      \
    } while (0)

    fx16 acc[2][2];
    #pragma unroll
    for (int m = 0; m < 2; ++m)
        #pragma unroll
        for (int n = 0; n < 2; ++n)
            #pragma unroll
            for (int r = 0; r < 16; ++r) acc[m][n][r] = 0.0f;

    const int t0 = sp * NTs;
    STAGE(t0, 0);
    #pragma unroll 1
    for (int tl = 0; tl < NTs; ++tl) {
        __syncthreads();
        if (tl + 1 < NTs) STAGE(t0 + tl + 1, (tl + 1) & 1);
        COMPUTE(tl & 1);
    }

    // ---- store f32 partials (C/D: col=lane&31, row=(r&3)+8*(r>>2)+4*(lane>>5))
    float* gp = gpart + (size_t)(cell * S + sp) * GPLANE
              + (size_t)(mblk * 128) * 4096 + hhblk * 32 + (lane & 31);
    #pragma unroll
    for (int m = 0; m < 2; ++m) {
        #pragma unroll
        for (int n = 0; n < 2; ++n) {
            const int gate = nw * 2 + n;
            #pragma unroll
            for (int r = 0; r < 16; ++r) {
                const int row = mw * 64 + m * 32 + 4 * (lane >> 5)
                              + (r & 3) + 8 * (r >> 2);
                gp[(size_t)row * 4096 + gate * 1024] = acc[m][n][r];
            }
        }
    }
    #undef STAGE
    #undef COMPUTE
}

// ---------------------------------------------------------------------------
// Reduce partials + gates + packed-h store (split-K epilogue).
// Block = (mblk, hhblk) tile: 128 b x 32 hh. grid (64, cnt).
// ---------------------------------------------------------------------------
__global__ __launch_bounds__(256)
void gates_red(const float* __restrict__ gpart, const float* __restrict__ bsum,
               float* __restrict__ c_buf, u16* __restrict__ hp,
               float* __restrict__ out, Stage st, int S)
{
    __shared__ u16 tbuf[128 * 33];

    const int u = blockIdx.x;
    const int cell = blockIdx.y;
    const int hhblk = 4 * (u & 7) + ((u >> 3) & 3);
    const int mblk  = u >> 5;
    const int node = st.node[cell], par = st.par[cell], layer = st.layer[cell];
    const int tid = threadIdx.x, wv = tid >> 6, lane = tid & 63;
    const int hhl = tid & 31, rg = tid >> 5;
    const int colg = hhblk * 32 + hhl;

    float bs4[4];
    #pragma unroll
    for (int g = 0; g < 4; ++g)
        bs4[g] = bsum[layer * 4096 + g * 1024 + colg];

    const float* cpar = c_buf + (size_t)(par * 2 + layer) * BH_ + colg;
    float*       cnew = c_buf + (size_t)(node * 2 + layer) * BH_ + colg;
    float*       outp = out + (size_t)(node - 1) * BH_ + colg;
    u16*         hpn  = hp + (size_t)(node * 2 + layer) * BH_;
    const float* gpc  = gpart + (size_t)cell * S * GPLANE;

    #pragma unroll 1
    for (int it = 0; it < 16; ++it) {
        const int row_l = it * 8 + rg;
        const size_t grow = (size_t)(mblk * 128 + row_l);
        float gv[4];
        #pragma unroll
        for (int g = 0; g < 4; ++g) {
            float s = bs4[g];
            #pragma unroll 1
            for (int sp = 0; sp < S; ++sp)
                s += gpc[(size_t)sp * GPLANE + grow * 4096 + g * 1024 + colg];
            gv[g] = s;
        }
        const float cp = cpar[grow * 1024];
        const float cn = sigf(gv[1]) * cp + sigf(gv[0]) * tanh_f(gv[2]);
        const float hn = sigf(gv[3]) * tanh_f(cn);
        cnew[grow * 1024] = cn;
        if (layer == 1) outp[grow * 1024] = hn;
        tbuf[row_l * 33 + hhl] = bf16_rn(hn);
    }
    __syncthreads();

    // pack h: 4 waves x 2 chunks (bt_local = wv, q = 0/1)
    #pragma unroll
    for (int q = 0; q < 2; ++q) {
        const int bt   = mblk * 4 + wv;
        const int k16h = hhblk * 2 + q;
        union { u16 s[8]; uint4 v; } pk;
        #pragma unroll
        for (int e = 0; e < 8; ++e)
            pk.s[e] = tbuf[(wv * 32 + (lane & 31)) * 33
                           + q * 16 + (lane >> 5) * 8 + e];
        *(uint4*)(hpn + ((size_t)bt * 64 + k16h) * 512 + lane * 8) = pk.v;
    }
}

// ---------------------------------------------------------------------------
extern "C" void kernel_launch(void* const* d_in, const int* in_sizes, int n_in,
                              void* d_out, int out_size, void* d_ws, size_t ws_size,
                              hipStream_t stream)
{
    const float* input  = (const float*)d_in[0];
    const float* bridge = (const float*)d_in[1];
    const float* Wih    = (const float*)d_in[2];
    const float* Whh    = (const float*)d_in[3];
    const float* bih    = (const float*)d_in[4];
    const float* bhh    = (const float*)d_in[5];
    float* out = (float*)d_out;

    u16* wp = (u16*)d_ws;
    u16* xp = wp + WPE;
    u16* hp = xp + XPE;
    float* c_buf = (float*)(hp + HPE);
    float* bsum  = c_buf + HPE;
    float* gpart = bsum + 8192;          // 8 planes x 4 MB = 32 MB

    hipMemsetAsync(hp, 0, (size_t)2 * BH_ * sizeof(u16), stream);
    hipMemsetAsync(c_buf, 0, (size_t)2 * BH_ * sizeof(float), stream);

    bias_sum_k<<<32, 256, 0, stream>>>(bih, bhh, bsum);
    pack_weights<<<8192, 256, 0, stream>>>(Wih, Whh, wp);
    pack_x<<<1920, 256, 0, stream>>>(input, bridge, xp);

    // Wavefront schedule: stage T = cells (node,layer) with depth(node)+layer==T
    static const Stage stages[7] = {
        { {1},                      {0},                      {0},                      1 },
        { {1,2,5,8},                {0,1,1,1},                {1,0,0,0},                4 },
        { {2,5,8,3,6,9,12},         {1,1,1,2,5,8,8},          {1,1,1,0,0,0,0},          7 },
        { {3,6,9,12,4,7,10,13},     {2,5,8,8,3,6,9,12},       {1,1,1,1,0,0,0,0},        8 },
        { {4,7,10,13,11,14},        {3,6,9,12,10,13},         {1,1,1,1,0,0},            6 },
        { {11,14,15},               {10,13,14},               {1,1,0},                  3 },
        { {15},                     {14},                     {1},                      1 },
    };
    static const int use_sk[7] = {1, 1, 0, 0, 0, 1, 1};
    static const int splits[7] = {4, 2, 0, 0, 0, 2, 4};

    for (int s = 0; s < 7; ++s) {
        const Stage& st = stages[s];
        if (use_sk[s]) {
            const int S = splits[s];
            cell_gemm_sk<<<dim3(st.cnt * 64 * S), 256, 0, stream>>>(
                wp, xp, hp, gpart, st, S, NT / S);
            gates_red<<<dim3(64, st.cnt), 256, 0, stream>>>(
                gpart, bsum, c_buf, hp, out, st, S);
        } else {
            cell_fused<<<dim3(st.cnt * 64), 256, 0, stream>>>(
                wp, xp, hp, c_buf, bsum, out, st);
        }
    }
}

// Round 11
// 299.078 us; speedup vs baseline: 4.0836x; 1.5561x over previous
//
#include <hip/hip_runtime.h>
#include <stdint.h>

typedef unsigned short u16;
typedef uint32_t u32;
typedef short s16x8 __attribute__((ext_vector_type(8)));
typedef float fx16 __attribute__((ext_vector_type(16)));

#define B_   256
#define H_   1024
#define BH_  (B_ * H_)                  // 262144
#define WPE  ((size_t)2 * 4096 * 2048)  // W pack elems
#define XPE  ((size_t)15 * BH_)
#define HPE  ((size_t)32 * BH_)
#define NT   32                         // K-steps (BK=64)
#define SLOT 24576                      // ring slot elems (48 KB): A 16384 + W 8192

struct Stage { int node[8]; int par[8]; int layer[8]; int cnt; };

__device__ __forceinline__ u16 bf16_rn(float x) {
    union { float f; u32 u; } v; v.f = x;
    return (u16)((v.u + 0x7FFFu + ((v.u >> 16) & 1u)) >> 16);
}
__device__ __forceinline__ float sigf(float x) {
    return __builtin_amdgcn_rcpf(1.0f + __expf(-x));
}
__device__ __forceinline__ float tanh_f(float x) {
    return 1.0f - 2.0f * __builtin_amdgcn_rcpf(1.0f + __expf(2.0f * x));
}

// ---------------------------------------------------------------------------
// Pack W into MFMA-B fragment order, bf16. Chunk w = ((layer*4+gate)*32+cg)*128+k16;
// lane l -> W[gate*1024+cg*32+(l&31)][k16*16+(l>>5)*8+e].
// ---------------------------------------------------------------------------
__global__ __launch_bounds__(256)
void pack_weights(const float* __restrict__ Wih, const float* __restrict__ Whh,
                  u16* __restrict__ wp)
{
    const int gt = blockIdx.x * 256 + threadIdx.x;
    const int w = gt >> 6, lane = gt & 63;
    const int k16 = w & 127, cg = (w >> 7) & 31, gate = (w >> 12) & 3, layer = w >> 14;
    const int row = gate * 1024 + cg * 32 + (lane & 31);
    const int k = k16 * 16 + (lane >> 5) * 8;
    const float* src = (k < 1024)
        ? Wih + ((size_t)layer * 4096 + row) * 1024 + k
        : Whh + ((size_t)layer * 4096 + row) * 1024 + (k - 1024);
    const float4 v0 = *(const float4*)src;
    const float4 v1 = *(const float4*)(src + 4);
    const float a[8] = {v0.x, v0.y, v0.z, v0.w, v1.x, v1.y, v1.z, v1.w};
    union { u16 s[8]; uint4 v; } hi;
    #pragma unroll
    for (int e = 0; e < 8; ++e) hi.s[e] = bf16_rn(a[e]);
    *(uint4*)(wp + (size_t)w * 512 + (size_t)lane * 8) = hi.v;
}

__global__ __launch_bounds__(256)
void pack_x(const float* __restrict__ input, const float* __restrict__ bridge,
            u16* __restrict__ xp)
{
    const int gt = blockIdx.x * 256 + threadIdx.x;
    const int w = gt >> 6, lane = gt & 63;
    const int k16 = w & 63, btile = (w >> 6) & 7, n1 = w >> 9;
    const int b = btile * 32 + (lane & 31);
    const int k = k16 * 16 + (lane >> 5) * 8;
    const float* src = (k < 512)
        ? input  + ((size_t)n1 * 256 + b) * 512 + k
        : bridge + ((size_t)n1 * 256 + b) * 512 + (k - 512);
    const float4 v0 = *(const float4*)src;
    const float4 v1 = *(const float4*)(src + 4);
    const float a[8] = {v0.x, v0.y, v0.z, v0.w, v1.x, v1.y, v1.z, v1.w};
    union { u16 s[8]; uint4 v; } hi;
    #pragma unroll
    for (int e = 0; e < 8; ++e) hi.s[e] = bf16_rn(a[e]);
    *(uint4*)(xp + (size_t)w * 512 + (size_t)lane * 8) = hi.v;
}

__global__ __launch_bounds__(256)
void bias_sum_k(const float* __restrict__ bih, const float* __restrict__ bhh,
                float* __restrict__ bs)
{
    const int i = blockIdx.x * 256 + threadIdx.x;
    if (i < 8192) bs[i] = bih[i] + bhh[i];
}

// ---------------------------------------------------------------------------
// Fused cell, ring-3 depth-2 pipeline. Block = 512 thr (8 waves).
// Tile: BM=256 (full batch; W staged ONCE per cell) x BN=128 (4 gates x 32 hh).
// Wave wv: rows wv*32..+31, all 4 gates -> acc[4] fx16 (64 VGPR).
// LDS ring: 3 x (A 32KB + W 16KB) = 144 KB, all via global_load_lds
// (6 instr/wave/step; NO register global loads in loop -> FIFO stays pure).
// Loop: wait vmcnt(6) [stage(t) landed, stage(t+1) in flight] -> s_barrier
// -> issue stage(t+2) -> compute(t). Depth-2 ~= 2 steps of in-flight time.
// 32 blocks/cell (hhblk); bid = cell*32+u, XCD = u%8 -> per-XCD W slice
// = 4 hhblk x 2 layers = 4 MB = its L2, stable across stages.
// ---------------------------------------------------------------------------
__global__ __launch_bounds__(512, 1)
void cell_fused(const u16* __restrict__ wp, const u16* __restrict__ xp,
                u16* __restrict__ hp, float* __restrict__ c_buf,
                const float* __restrict__ bsum, float* __restrict__ out,
                Stage st)
{
    __shared__ u16 SM[3 * SLOT];        // 144 KB

    const int bid  = blockIdx.x;
    const int cell = bid >> 5;
    const int u    = bid & 31;
    const int hhblk = 4 * (u & 7) + (u >> 3);      // XCD-stable grouping
    const int node = st.node[cell], par = st.par[cell], layer = st.layer[cell];
    const int tid = threadIdx.x, wv = tid >> 6, lane = tid & 63;
    const int tq  = tid >> 8;            // 0/1
    const int kks = (tid >> 6) & 3;      // staging kk slot
    const int e8  = (tid & 63) * 8;      // staging element offset

    // A segment bases (seg0 = K 0..1023, seg1 = K 1024..2047)
    const u16 *A0, *A1;
    if (layer == 0) {
        A0 = xp + (size_t)(node - 1) * BH_;
        A1 = hp + (size_t)(par * 2 + 0) * BH_;
    } else {
        A0 = hp + (size_t)(node * 2 + 0) * BH_;
        A1 = hp + (size_t)(par * 2 + 1) * BH_;
    }
    // W source base per staging instr i (gate g = 2i + tq); + T*2048 per step
    size_t wsg[2];
    #pragma unroll
    for (int i = 0; i < 2; ++i)
        wsg[i] = (size_t)((layer * 4 + (2 * i + tq)) * 32 + hhblk) * 65536
               + (size_t)kks * 512 + e8;

    // stage step T into ring slot S: A 4 instr (bt = 2i+tq), W 2 instr
    #define STAGE(T, S) do {                                                   \
        const u16* As_ = ((T) < 16) ? A0 : A1;                                 \
        const size_t ab_ = ((size_t)((T) & 15) * 4 + kks) * 512 + e8;          \
        _Pragma("unroll")                                                      \
        for (int i_ = 0; i_ < 4; ++i_) {                                       \
            __builtin_amdgcn_global_load_lds(                                  \
                (const __attribute__((address_space(1))) void*)                \
                    (As_ + (size_t)(2 * i_ + tq) * 32768 + ab_),               \
                (__attribute__((address_space(3))) void*)                      \
                    (SM + (S) * SLOT + i_ * 4096 + tid * 8),                   \
                16, 0, 0);                                                     \
        }                                                                      \
        _Pragma("unroll")                                                      \
        for (int i_ = 0; i_ < 2; ++i_) {                                       \
            __builtin_amdgcn_global_load_lds(                                  \
                (const __attribute__((address_space(1))) void*)                \
                    (wp + wsg[i_] + (size_t)(T) * 2048),                       \
                (__attribute__((address_space(3))) void*)                      \
                    (SM + (S) * SLOT + 16384 + i_ * 4096 + tid * 8),           \
                16, 0, 0);                                                     \
        }                                                                      \
    } while (0)

    #define COMPUTE(S) do {                                                    \
        _Pragma("unroll")                                                      \
        for (int kk_ = 0; kk_ < 4; ++kk_) {                                    \
            const s16x8 a_ = *(const s16x8*)                                   \
                (SM + (S) * SLOT + wv * 2048 + kk_ * 512 + lane * 8);          \
            _Pragma("unroll")                                                  \
            for (int g_ = 0; g_ < 4; ++g_) {                                   \
                const s16x8 w_ = *(const s16x8*)                               \
                    (SM + (S) * SLOT + 16384 + g_ * 2048 + kk_ * 512           \
                     + lane * 8);                                              \
                acc[g_] = __builtin_amdgcn_mfma_f32_32x32x16_bf16(             \
                    a_, w_, acc[g_], 0, 0, 0);                                 \
            }                                                                  \
        }                                                                      \
    } while (0)

    fx16 acc[4];
    #pragma unroll
    for (int g = 0; g < 4; ++g)
        #pragma unroll
        for (int r = 0; r < 16; ++r) acc[g][r] = 0.0f;

    // prologue: 12 outstanding per wave
    STAGE(0, 0);
    STAGE(1, 1);

    #pragma unroll 1
    for (int t = 0; t < NT; ++t) {
        // retire exactly stage(t)'s 6; stage(t+1)'s 6 stay in flight
        asm volatile("s_waitcnt vmcnt(6)" ::: "memory");
        __builtin_amdgcn_s_barrier();
        const int sT = (t + 2 < NT) ? (t + 2) : (NT - 1);  // tail dummies: same
        STAGE(sT, (t + 2) % 3);                            // data, retired slot
        COMPUTE(t % 3);
    }
    __syncthreads();   // drains vmcnt(0): tail dummies land before LDS reuse

    // ---- fused gates epilogue (C/D: col=lane&31, row=(r&3)+8*(r>>2)+4*(lane>>5))
    const int col  = lane & 31;
    const int colg = hhblk * 32 + col;
    float bs4[4];
    #pragma unroll
    for (int g = 0; g < 4; ++g)
        bs4[g] = bsum[layer * 4096 + g * 1024 + colg];

    const float* cpar = c_buf + (size_t)(par * 2 + layer) * BH_ + colg;
    float*       cnew = c_buf + (size_t)(node * 2 + layer) * BH_ + colg;
    float*       outp = out + (size_t)(node - 1) * BH_ + colg;
    u16*         hpn  = hp + (size_t)(node * 2 + layer) * BH_;

    u32* hq = (u32*)(&SM[0]) + wv * 1056;   // per-wave 32x33 u32 scratch

    #pragma unroll
    for (int r = 0; r < 16; ++r) {
        const int rl = 4 * (lane >> 5) + (r & 3) + 8 * (r >> 2);
        const size_t row = (size_t)(wv * 32 + rl) * 1024;
        const float gi = acc[0][r] + bs4[0];
        const float gf = acc[1][r] + bs4[1];
        const float gg = acc[2][r] + bs4[2];
        const float go = acc[3][r] + bs4[3];
        const float cp = cpar[row];
        const float cn = sigf(gf) * cp + sigf(gi) * tanh_f(gg);
        const float hn = sigf(go) * tanh_f(cn);
        cnew[row] = cn;
        if (layer == 1) outp[row] = hn;
        hq[rl * 33 + col] = (u32)bf16_rn(hn);
    }

    // ---- transpose h (wave-local) into packed A-frag chunks for next cells
    #pragma unroll
    for (int q = 0; q < 2; ++q) {
        const int k16h = hhblk * 2 + q;
        union { u16 s[8]; uint4 v; } pk;
        #pragma unroll
        for (int e = 0; e < 8; ++e)
            pk.s[e] = (u16)hq[(lane & 31) * 33 + q * 16 + (lane >> 5) * 8 + e];
        *(uint4*)(hpn + ((size_t)wv * 64 + k16h) * 512 + lane * 8) = pk.v;
    }
    #undef STAGE
    #undef COMPUTE
}

// ---------------------------------------------------------------------------
extern "C" void kernel_launch(void* const* d_in, const int* in_sizes, int n_in,
                              void* d_out, int out_size, void* d_ws, size_t ws_size,
                              hipStream_t stream)
{
    const float* input  = (const float*)d_in[0];
    const float* bridge = (const float*)d_in[1];
    const float* Wih    = (const float*)d_in[2];
    const float* Whh    = (const float*)d_in[3];
    const float* bih    = (const float*)d_in[4];
    const float* bhh    = (const float*)d_in[5];
    float* out = (float*)d_out;

    u16* wp = (u16*)d_ws;
    u16* xp = wp + WPE;
    u16* hp = xp + XPE;
    float* c_buf = (float*)(hp + HPE);
    float* bsum  = c_buf + HPE;

    hipMemsetAsync(hp, 0, (size_t)2 * BH_ * sizeof(u16), stream);
    hipMemsetAsync(c_buf, 0, (size_t)2 * BH_ * sizeof(float), stream);

    bias_sum_k<<<32, 256, 0, stream>>>(bih, bhh, bsum);
    pack_weights<<<8192, 256, 0, stream>>>(Wih, Whh, wp);
    pack_x<<<1920, 256, 0, stream>>>(input, bridge, xp);

    // Wavefront schedule: stage T = cells (node,layer) with depth(node)+layer==T
    static const Stage stages[7] = {
        { {1},                      {0},                      {0},                      1 },
        { {1,2,5,8},                {0,1,1,1},                {1,0,0,0},                4 },
        { {2,5,8,3,6,9,12},         {1,1,1,2,5,8,8},          {1,1,1,0,0,0,0},          7 },
        { {3,6,9,12,4,7,10,13},     {2,5,8,8,3,6,9,12},       {1,1,1,1,0,0,0,0},        8 },
        { {4,7,10,13,11,14},        {3,6,9,12,10,13},         {1,1,1,1,0,0},            6 },
        { {11,14,15},               {10,13,14},               {1,1,0},                  3 },
        { {15},                     {14},                     {1},                      1 },
    };

    for (int s = 0; s < 7; ++s) {
        cell_fused<<<dim3(stages[s].cnt * 32), 512, 0, stream>>>(
            wp, xp, hp, c_buf, bsum, out, stages[s]);
    }
}